// Round 6
// baseline (339.722 us; speedup 1.0000x reference)
//
#include <hip/hip_runtime.h>
#include <hip/hip_cooperative_groups.h>
#include <cstdint>

namespace cg = cooperative_groups;

#define N_IDE 4096
#define M_U   16384
#define D_DIM 256
#define EPSF  1e-12f
#define INV_M (1.0f / 16384.0f)

typedef _Float16 f16x8 __attribute__((ext_vector_type(8)));
typedef float    f32x4 __attribute__((ext_vector_type(4)));

// ---- async global->LDS 16B copy. LDS dest = wave-uniform base + lane*16. ----
__device__ __forceinline__ void gll16(const void* g, void* l) {
  __builtin_amdgcn_global_load_lds(
      (const __attribute__((address_space(1))) void*)(uintptr_t)g,
      (__attribute__((address_space(3))) void*)(uint32_t)(uintptr_t)l,
      16, 0, 0);
}

__device__ __forceinline__ unsigned short f2h_bits(float f) {
  _Float16 h = (_Float16)f;
  return __builtin_bit_cast(unsigned short, h);
}

#define SBAR()  asm volatile("s_barrier" ::: "memory")

// ---- Single cooperative kernel: conv | GEMM+dist | dsum | loss ----
// 256 blocks x 512 threads = exactly 1 block/CU (co-residency guaranteed:
// 132 KB LDS, <=256 regs/wave at 2 waves/SIMD). Four phases separated by
// grid.sync(); eliminates ~18 us/launch x 3 inter-kernel boundaries.
// Phase 1 GEMM is BIT-IDENTICAL to r4/r5's k_gemm body, wrapped in a
// 4-round loop (block handles bm = blk>>4, bn = (blk&15)*4 + round).
__global__ __launch_bounds__(512, 2) void k_all(const float* __restrict__ ide,
                                                const float* __restrict__ u,
                                                unsigned short* __restrict__ Ah,
                                                unsigned short* __restrict__ Bh,
                                                float* __restrict__ x2,
                                                float* __restrict__ y2,
                                                float* __restrict__ partial,
                                                float* __restrict__ dvec,
                                                float* __restrict__ out) {
  __shared__ __align__(16) unsigned short sA[2][16384];   // 64 KB
  __shared__ __align__(16) unsigned short sB[2][16384];   // 64 KB
  __shared__ float rowacc[4][256];                        // 4 KB
  __shared__ float wsum[8];

  cg::grid_group grid = cg::this_grid();

  const int t   = threadIdx.x;
  const int w   = t >> 6;
  const int l   = t & 63;
  const int blk = blockIdx.x;

  // ================= phase 0: fp32 -> f16 convert + row norms =================
  if (blk == 0 && t == 0) out[0] = 0.f;
  {
    const int gwid = blk * 8 + w;            // 2048 waves, 10 rows each
#pragma unroll
    for (int it = 0; it < 10; ++it) {
      const int r = gwid + it * 2048;        // 0..20479
      const float4* src; ushort4* dst; float* nrm;
      if (r < N_IDE) {
        src = (const float4*)(ide + (size_t)r * D_DIM);
        dst = (ushort4*)(Ah + (size_t)r * D_DIM);
        nrm = x2 + r;
      } else {
        const int rb = r - N_IDE;
        src = (const float4*)(u + (size_t)rb * D_DIM);
        dst = (ushort4*)(Bh + (size_t)rb * D_DIM);
        nrm = y2 + rb;
      }
      float4 v = src[l];
      float s = v.x * v.x + v.y * v.y + v.z * v.z + v.w * v.w;
      ushort4 o;
      o.x = f2h_bits(v.x); o.y = f2h_bits(v.y);
      o.z = f2h_bits(v.z); o.w = f2h_bits(v.w);
      dst[l] = o;
#pragma unroll
      for (int m = 1; m <= 32; m <<= 1) s += __shfl_xor(s, m, 64);
      if (l == 0) *nrm = s;
    }
  }
  __threadfence();
  grid.sync();

  // ================= phase 1: MFMA GEMM + dist epilogue (4 tile-rounds) ======
  const int lrow = l & 15;
  const int lhi  = l >> 4;
  const int wm   = w >> 2, wn = w & 3;       // 2x4 wave grid
  const int bm   = blk >> 4;                 // 0..15 row-tiles
  const int gcol = blk & 15;                 // col-group of 4 bn-tiles

  // staging source offset (pre-swizzled): row r=t>>3, slot s=t&7, kc=s^(r&7)
  const int sr  = t >> 3;
  const int skc = (t & 7) ^ (sr & 7);
  const size_t soff = (size_t)sr * D_DIM + (size_t)skc * 8;
  // read-side swizzled slot offsets (lane-const)
  const int sl0 = ((lhi)     ^ (lrow & 7)) * 8;
  const int sl1 = ((lhi + 4) ^ (lrow & 7)) * 8;

  const unsigned short* Abase = Ah + (size_t)bm * 256 * D_DIM;

#pragma unroll 1
  for (int rnd = 0; rnd < 4; ++rnd) {
    const int bn = gcol * 4 + rnd;
    const unsigned short* Bbase = Bh + (size_t)bn * 256 * D_DIM;

    auto stA = [&](int k1, int h) {
      const unsigned short* src = Abase + (size_t)h * 128 * D_DIM + k1 * 64 + soff;
      unsigned short* dst = &sA[k1 & 1][h * 8192 + w * 512];
      gll16(src, dst);
      gll16(src + 64 * D_DIM, dst + 4096);
    };
    auto stB = [&](int k1, int h) {
      const unsigned short* src = Bbase + (size_t)h * 128 * D_DIM + k1 * 64 + soff;
      unsigned short* dst = &sB[k1 & 1][h * 8192 + w * 512];
      gll16(src, dst);
      gll16(src + 64 * D_DIM, dst + 4096);
    };

    // ---- prologue: stage K-tile 0 (A+B), drain, publish ----
    stA(0, 0); stA(0, 1);
    stB(0, 0); stB(0, 1);
    asm volatile("s_waitcnt vmcnt(0)" ::: "memory");
    SBAR();

    f16x8 afA[4], afB[4], bf0[4], bf1[4];
    {
      const unsigned short* Ab0 = &sA[0][wm * 8192 + lrow * 64];
      const unsigned short* Bb0 = &sB[0][(wn >> 1) * 8192 + ((wn & 1) * 64 + lrow) * 64];
#pragma unroll
      for (int nj = 0; nj < 4; ++nj)
        bf0[nj] = *(const f16x8*)(Bb0 + nj * 1024 + sl0);
#pragma unroll
      for (int mi = 0; mi < 4; ++mi)
        afA[mi] = *(const f16x8*)(Ab0 + mi * 1024 + sl0);
    }

    f32x4 acc[8][4];
#pragma unroll
    for (int mi = 0; mi < 8; ++mi)
#pragma unroll
      for (int nj = 0; nj < 4; ++nj)
        acc[mi][nj] = (f32x4){0.f, 0.f, 0.f, 0.f};

#pragma unroll
    for (int kt = 0; kt < 4; ++kt) {
      const unsigned short* Ab = &sA[kt & 1][wm * 8192 + lrow * 64];
      const unsigned short* Bb = &sB[kt & 1][(wn >> 1) * 8192 + ((wn & 1) * 64 + lrow) * 64];

      // ---- w0: MFMA(afA x bf0); read afB(sl0 hi); stage kt+1 ----
      __builtin_amdgcn_s_setprio(1);
#pragma unroll
      for (int mi = 0; mi < 4; ++mi)
#pragma unroll
        for (int nj = 0; nj < 4; ++nj)
          acc[mi][nj] = __builtin_amdgcn_mfma_f32_16x16x32_f16(afA[mi], bf0[nj],
                                                               acc[mi][nj], 0, 0, 0);
      __builtin_amdgcn_s_setprio(0);
#pragma unroll
      for (int mi = 0; mi < 4; ++mi)
        afB[mi] = *(const f16x8*)(Ab + (64 + mi * 16) * 64 + sl0);
      if (kt < 3) { stA(kt + 1, 0); stA(kt + 1, 1); stB(kt + 1, 0); stB(kt + 1, 1); }
      SBAR();

      // ---- w1: MFMA(afB x bf0); read afA(sl1 lo) + bf1(sl1) ----
      __builtin_amdgcn_s_setprio(1);
#pragma unroll
      for (int mi = 0; mi < 4; ++mi)
#pragma unroll
        for (int nj = 0; nj < 4; ++nj)
          acc[4 + mi][nj] = __builtin_amdgcn_mfma_f32_16x16x32_f16(afB[mi], bf0[nj],
                                                                   acc[4 + mi][nj], 0, 0, 0);
      __builtin_amdgcn_s_setprio(0);
#pragma unroll
      for (int mi = 0; mi < 4; ++mi)
        afA[mi] = *(const f16x8*)(Ab + mi * 1024 + sl1);
#pragma unroll
      for (int nj = 0; nj < 4; ++nj)
        bf1[nj] = *(const f16x8*)(Bb + nj * 1024 + sl1);
      SBAR();

      // ---- w2: MFMA(afA x bf1); read afB(sl1 hi); vmcnt; publish ----
      __builtin_amdgcn_s_setprio(1);
#pragma unroll
      for (int mi = 0; mi < 4; ++mi)
#pragma unroll
        for (int nj = 0; nj < 4; ++nj)
          acc[mi][nj] = __builtin_amdgcn_mfma_f32_16x16x32_f16(afA[mi], bf1[nj],
                                                               acc[mi][nj], 0, 0, 0);
      __builtin_amdgcn_s_setprio(0);
#pragma unroll
      for (int mi = 0; mi < 4; ++mi)
        afB[mi] = *(const f16x8*)(Ab + (64 + mi * 16) * 64 + sl1);
      if (kt < 3) asm volatile("s_waitcnt vmcnt(0)" ::: "memory");
      SBAR();   // buf kt+1 published here

      // ---- w3: MFMA(afB x bf1); read kt+1's first fragments ----
      __builtin_amdgcn_s_setprio(1);
#pragma unroll
      for (int mi = 0; mi < 4; ++mi)
#pragma unroll
        for (int nj = 0; nj < 4; ++nj)
          acc[4 + mi][nj] = __builtin_amdgcn_mfma_f32_16x16x32_f16(afB[mi], bf1[nj],
                                                                   acc[4 + mi][nj], 0, 0, 0);
      __builtin_amdgcn_s_setprio(0);
      if (kt < 3) {
        const unsigned short* Abn = &sA[(kt + 1) & 1][wm * 8192 + lrow * 64];
        const unsigned short* Bbn = &sB[(kt + 1) & 1][(wn >> 1) * 8192 + ((wn & 1) * 64 + lrow) * 64];
#pragma unroll
        for (int nj = 0; nj < 4; ++nj)
          bf0[nj] = *(const f16x8*)(Bbn + nj * 1024 + sl0);
#pragma unroll
        for (int mi = 0; mi < 4; ++mi)
          afA[mi] = *(const f16x8*)(Abn + mi * 1024 + sl0);
      }
      SBAR();
    }

    // ---- dist epilogue over this tile's 256 cols ----
    float yv[4];
#pragma unroll
    for (int nj = 0; nj < 4; ++nj)
      yv[nj] = y2[bn * 256 + wn * 64 + nj * 16 + lrow];

#pragma unroll
    for (int mi = 0; mi < 8; ++mi) {
      float4 x2v = *(const float4*)&x2[bm * 256 + wm * 128 + mi * 16 + lhi * 4];
      float xr[4] = {x2v.x, x2v.y, x2v.z, x2v.w};
      float rv[4];
#pragma unroll
      for (int rr = 0; rr < 4; ++rr) {
        float ssum = 0.f;
#pragma unroll
        for (int nj = 0; nj < 4; ++nj) {
          float d2 = xr[rr] + yv[nj] - 2.0f * acc[mi][nj][rr];
          d2 = fmaxf(d2, 0.0f);
          ssum += __builtin_amdgcn_sqrtf(d2 + EPSF);
        }
        ssum += __shfl_xor(ssum, 1, 64);
        ssum += __shfl_xor(ssum, 2, 64);
        ssum += __shfl_xor(ssum, 4, 64);
        ssum += __shfl_xor(ssum, 8, 64);
        rv[rr] = ssum;
      }
      if (lrow == 0)
        *(float4*)&rowacc[wn][wm * 128 + mi * 16 + lhi * 4] =
            make_float4(rv[0], rv[1], rv[2], rv[3]);
    }

    __syncthreads();
    if (t < 256)
      partial[(size_t)bn * N_IDE + bm * 256 + t] =
          rowacc[0][t] + rowacc[1][t] + rowacc[2][t] + rowacc[3][t];
  }
  __threadfence();
  grid.sync();

  // ================= phase 2: d[k] = sum over 64 bn-slices ===================
  // wave per row (lane = slice), 2 rounds -> 16 rows/block, 4096 total.
#pragma unroll
  for (int q = 0; q < 2; ++q) {
    const int row = blk * 16 + q * 8 + w;
    float v = partial[(size_t)l * N_IDE + row];
#pragma unroll
    for (int m = 1; m <= 32; m <<= 1) v += __shfl_xor(v, m, 64);
    if (l == 0) dvec[row] = v;
  }
  __threadfence();
  grid.sync();

  // ================= phase 3: loss = sum_ij sqrt(((d_i-d_j)/M)^2+eps) ========
  float* sd = (float*)&sA[0][0];          // reuse GEMM LDS (16 KB needed)
  for (int k = t; k < N_IDE; k += 512) sd[k] = dvec[k];
  __syncthreads();
  {
    const int gtid = blk * 512 + t;       // 131072 threads: 32 per i
    const int i  = gtid >> 5;
    const int jl = gtid & 31;
    const float di = sd[i];
    float s = 0.f;
    for (int k = 0; k < 128; ++k) {
      float diff = (di - sd[jl + k * 32]) * INV_M;
      s += __builtin_amdgcn_sqrtf(diff * diff + EPSF);
    }
#pragma unroll
    for (int m = 1; m <= 32; m <<= 1) s += __shfl_xor(s, m, 64);
    if (l == 0) wsum[w] = s;
    __syncthreads();
    if (t == 0) {
      float tot = 0.f;
#pragma unroll
      for (int q = 0; q < 8; ++q) tot += wsum[q];
      atomicAdd(out, tot);
    }
  }
}

extern "C" void kernel_launch(void* const* d_in, const int* in_sizes, int n_in,
                              void* d_out, int out_size, void* d_ws, size_t ws_size,
                              hipStream_t stream) {
  (void)in_sizes; (void)n_in; (void)out_size; (void)ws_size;
  const float* ide = (const float*)d_in[0];
  const float* u   = (const float*)d_in[1];
  float* out = (float*)d_out;

  char* ws = (char*)d_ws;
  size_t off = 0;
  unsigned short* Ah = (unsigned short*)(ws + off); off += (size_t)N_IDE * D_DIM * 2;  // 2 MB
  unsigned short* Bh = (unsigned short*)(ws + off); off += (size_t)M_U  * D_DIM * 2;   // 8 MB
  float* x2      = (float*)(ws + off); off += (size_t)N_IDE * 4;
  float* y2      = (float*)(ws + off); off += (size_t)M_U * 4;
  float* partial = (float*)(ws + off); off += (size_t)64 * N_IDE * 4;                  // 1 MB
  float* dvec    = (float*)(ws + off); off += (size_t)N_IDE * 4;

  void* args[] = {(void*)&ide, (void*)&u, (void*)&Ah, (void*)&Bh, (void*)&x2,
                  (void*)&y2, (void*)&partial, (void*)&dvec, (void*)&out};
  hipLaunchCooperativeKernel((void*)k_all, dim3(256), dim3(512), args, 0, stream);
}

// Round 7
// 125.823 us; speedup vs baseline: 2.7000x; 2.7000x over previous
//
#include <hip/hip_runtime.h>
#include <hip/hip_bf16.h>
#include <cstdint>

#define N_IDE 4096
#define M_U   16384
#define D_DIM 256
#define EPSF  1e-12f
#define INV_M (1.0f / 16384.0f)

#define CGC   512                 // columns per column-group tile
#define BK    32                  // K per step
#define SB_ELEMS (CGC * BK)       // 16384 f16 = 32 KB

typedef _Float16 f16x8 __attribute__((ext_vector_type(8)));
typedef float    f32x4 __attribute__((ext_vector_type(4)));

// ---- async global->LDS 16B copy. LDS dest = wave-uniform base + lane*16. ----
__device__ __forceinline__ void gll16(const void* g, void* l) {
  __builtin_amdgcn_global_load_lds(
      (const __attribute__((address_space(1))) void*)(uintptr_t)g,
      (__attribute__((address_space(3))) void*)(uint32_t)(uintptr_t)l,
      16, 0, 0);
}

__device__ __forceinline__ unsigned short f2h_bits(float f) {
  _Float16 h = (_Float16)f;
  return __builtin_bit_cast(unsigned short, h);
}

// ---- Kernel 1: fp32 -> f16 convert + row squared-norms (one wave per row) ----
__global__ __launch_bounds__(256) void k_conv(const float* __restrict__ ide,
                                              const float* __restrict__ u,
                                              unsigned short* __restrict__ Ah,
                                              unsigned short* __restrict__ Bh,
                                              float* __restrict__ x2,
                                              float* __restrict__ y2,
                                              float* __restrict__ out) {
  if (blockIdx.x == 0 && threadIdx.x == 0) out[0] = 0.f;   // replaces memset launch
  int gw = (blockIdx.x * 256 + threadIdx.x) >> 6;
  int l  = threadIdx.x & 63;
  const float4* src;
  ushort4* dst;
  float* nrm;
  if (gw < N_IDE) {
    src = (const float4*)(ide + (size_t)gw * D_DIM);
    dst = (ushort4*)(Ah + (size_t)gw * D_DIM);
    nrm = x2 + gw;
  } else {
    int r = gw - N_IDE;
    src = (const float4*)(u + (size_t)r * D_DIM);
    dst = (ushort4*)(Bh + (size_t)r * D_DIM);
    nrm = y2 + r;
  }
  float4 v = src[l];
  float s = v.x * v.x + v.y * v.y + v.z * v.z + v.w * v.w;
  ushort4 o;
  o.x = f2h_bits(v.x); o.y = f2h_bits(v.y);
  o.z = f2h_bits(v.z); o.w = f2h_bits(v.w);
  dst[l] = o;
#pragma unroll
  for (int m = 1; m <= 32; m <<= 1) s += __shfl_xor(s, m, 64);
  if (l == 0) *nrm = s;
}

// ---- Kernel 2: persistent-A MFMA GEMM, 512 threads (8 waves, 2/SIMD) ----
// grid (8, 32): by = 128-row group; bx picks 4 of 32 column-groups (512 cols).
// LDS: A 128x256 f16 (64KB, swizzled, staged once)
//    + B double-buffer 2 x (512 cols x 32 K) f16 (2x32KB, natural layout:
//      64B row pitch makes fragment wave-reads contiguous 1KB -> conflict-free)
// Steps: s = cg*8 + kt, cg in 0..3, kt in 0..7. One-step-ahead B prefetch.
// Output: partial[bx][grow] = sum of dist over this block's 2048 columns.
// [r0-proven fastest GEMM variant: 53.6 us, MfmaUtil 26%, kept verbatim]
__global__ __launch_bounds__(512, 2) void k_gemm(const unsigned short* __restrict__ Ah,
                                                 const unsigned short* __restrict__ Bh,
                                                 const float* __restrict__ x2,
                                                 const float* __restrict__ y2,
                                                 float* __restrict__ partial) {
  __shared__ __align__(16) unsigned short sA[128 * 256];      // 64 KB
  __shared__ __align__(16) unsigned short sB[2 * SB_ELEMS];   // 64 KB
  __shared__ float rowacc[4][128];                            // per-wn slices

  const int t    = threadIdx.x;
  const int w    = t >> 6;
  const int l    = t & 63;
  const int wm   = w >> 2, wn = w & 3;   // 2x4 wave grid; wave tile 64x128
  const int lrow = l & 15;
  const int lhi  = l >> 4;
  const int bx   = blockIdx.x;           // 0..7
  const int by   = blockIdx.y;           // 0..31

  rowacc[t >> 7][t & 127] = 0.f;         // 512 threads cover 4x128 exactly

  // ---- stage A (128 rows x 256 K), XOR-swizzled in 16B chunks ----
#pragma unroll
  for (int i = 0; i < 8; ++i) {
    int L = i * 512 + t;                 // chunk id 0..4095
    int row = L >> 5;
    int p = L & 31;
    int c = (p & 24) | ((p & 7) ^ (row & 7));
    gll16(Ah + (size_t)(by * 128 + row) * D_DIM + c * 8,
          sA + (size_t)(i * 512 + w * 64) * 8);
  }

  // ---- B tile stage: flat step s -> buf s&1 (natural layout, no swizzle) ----
  auto stageB = [&](int s) {
    const int cgi = (s >> 3) * 8 + bx;   // column-group 0..31
    const int kt  = s & 7;
    const unsigned short* src = Bh + (size_t)cgi * CGC * D_DIM + kt * BK;
    unsigned short* dstb = sB + (size_t)(s & 1) * SB_ELEMS;
#pragma unroll
    for (int j = 0; j < 4; ++j) {
      int L = j * 512 + t;               // chunk id 0..2047
      int row = L >> 2;                  // B row (= C column) 0..511
      int c = L & 3;                     // 16B chunk within 64B row
      gll16(src + (size_t)row * D_DIM + c * 8,
            dstb + (size_t)(j * 512 + w * 64) * 8);
    }
  };

  // x2 for this wave's rows, loaded once (rr 0..3 contiguous -> float4)
  float4 x2v[4];
#pragma unroll
  for (int mi = 0; mi < 4; ++mi)
    x2v[mi] = *(const float4*)&x2[by * 128 + wm * 64 + mi * 16 + lhi * 4];

  stageB(0);
  __syncthreads();    // barrier drains vmcnt(0): A + B(step 0) ready

  for (int cg = 0; cg < 4; ++cg) {
    const int cgi = cg * 8 + bx;

    f32x4 acc[4][8];
#pragma unroll
    for (int mi = 0; mi < 4; ++mi)
#pragma unroll
      for (int ni = 0; ni < 8; ++ni)
        acc[mi][ni] = (f32x4){0.f, 0.f, 0.f, 0.f};

    for (int kt = 0; kt < 8; ++kt) {
      const int s = cg * 8 + kt;
      if (s + 1 < 32) stageB(s + 1);     // prefetch into other buffer

      // A fragments: logical chunk kt*4+lhi, physical = swizzled
      f16x8 af[4];
#pragma unroll
      for (int mi = 0; mi < 4; ++mi) {
        int arow = wm * 64 + mi * 16 + lrow;
        int lc   = kt * 4 + lhi;
        int pc   = (lc & 24) | ((lc & 7) ^ (lrow & 7));
        af[mi] = *(const f16x8*)(sA + (size_t)arow * 256 + pc * 8);
      }

      const unsigned short* bbuf = sB + (size_t)(s & 1) * SB_ELEMS;
#pragma unroll
      for (int half = 0; half < 2; ++half) {
        f16x8 bf[4];
#pragma unroll
        for (int nj = 0; nj < 4; ++nj) {
          int brow = wn * 128 + (half * 4 + nj) * 16 + lrow;
          bf[nj] = *(const f16x8*)(bbuf + (size_t)brow * BK + lhi * 8);
        }
#pragma unroll
        for (int mi = 0; mi < 4; ++mi)
#pragma unroll
          for (int nj = 0; nj < 4; ++nj)
            acc[mi][half * 4 + nj] =
                __builtin_amdgcn_mfma_f32_16x16x32_f16(af[mi], bf[nj],
                                                       acc[mi][half * 4 + nj], 0, 0, 0);
      }
      __syncthreads();   // prefetch drained; buffer swap safe
    }

    // ---- epilogue: dist + row partial sums into this wave's rowacc slice ----
    float yv[8];
#pragma unroll
    for (int ni = 0; ni < 8; ++ni)
      yv[ni] = y2[cgi * CGC + wn * 128 + ni * 16 + lrow];

#pragma unroll
    for (int mi = 0; mi < 4; ++mi) {
      float xr[4] = {x2v[mi].x, x2v[mi].y, x2v[mi].z, x2v[mi].w};
#pragma unroll
      for (int rr = 0; rr < 4; ++rr) {
        float ssum = 0.f;
#pragma unroll
        for (int ni = 0; ni < 8; ++ni) {
          float d2 = xr[rr] + yv[ni] - 2.0f * acc[mi][ni][rr];
          d2 = fmaxf(d2, 0.0f);
          ssum += __builtin_amdgcn_sqrtf(d2 + EPSF);
        }
        ssum += __shfl_xor(ssum, 1, 64);
        ssum += __shfl_xor(ssum, 2, 64);
        ssum += __shfl_xor(ssum, 4, 64);
        ssum += __shfl_xor(ssum, 8, 64);
        if (lrow == 0)
          rowacc[wn][wm * 64 + mi * 16 + lhi * 4 + rr] += ssum;  // wave-private slice
      }
    }
  }

  __syncthreads();
  if (t < 128)
    partial[(size_t)bx * N_IDE + by * 128 + t] =
        rowacc[0][t] + rowacc[1][t] + rowacc[2][t] + rowacc[3][t];
}

// ---- Kernel 3: loss = sum_{i,j} sqrt(((d_i-d_j))^2 + eps), d from partials ----
__global__ __launch_bounds__(256) void k_loss(const float* __restrict__ partial,
                                              float* __restrict__ out) {
  __shared__ float sd[N_IDE];
  __shared__ float wsum[4];
  int t = threadIdx.x;
  for (int k = t; k < N_IDE; k += 256) {
    float s = 0.f;
#pragma unroll
    for (int b = 0; b < 8; ++b) s += partial[(size_t)b * N_IDE + k];
    sd[k] = s;
  }
  __syncthreads();
  int tid = blockIdx.x * 256 + t;   // 65536 threads: 16 per i
  int i   = tid >> 4;
  int jl  = tid & 15;
  float di = sd[i];
  float s  = 0.f;
  for (int k = 0; k < 256; ++k) {
    float diff = (di - sd[jl + k * 16]) * INV_M;
    s += __builtin_amdgcn_sqrtf(diff * diff + EPSF);
  }
#pragma unroll
  for (int m = 1; m <= 32; m <<= 1) s += __shfl_xor(s, m, 64);
  if ((t & 63) == 0) wsum[t >> 6] = s;
  __syncthreads();
  if (t == 0) atomicAdd(out, wsum[0] + wsum[1] + wsum[2] + wsum[3]);
}

extern "C" void kernel_launch(void* const* d_in, const int* in_sizes, int n_in,
                              void* d_out, int out_size, void* d_ws, size_t ws_size,
                              hipStream_t stream) {
  (void)in_sizes; (void)n_in; (void)out_size; (void)ws_size;
  const float* ide = (const float*)d_in[0];
  const float* u   = (const float*)d_in[1];
  float* out = (float*)d_out;

  char* ws = (char*)d_ws;
  size_t off = 0;
  unsigned short* Ah = (unsigned short*)(ws + off); off += (size_t)N_IDE * D_DIM * 2;  // 2 MB
  unsigned short* Bh = (unsigned short*)(ws + off); off += (size_t)M_U  * D_DIM * 2;   // 8 MB
  float* x2      = (float*)(ws + off); off += (size_t)N_IDE * 4;
  float* y2      = (float*)(ws + off); off += (size_t)M_U * 4;
  float* partial = (float*)(ws + off); off += (size_t)8 * N_IDE * 4;                   // 128 KB

  k_conv<<<(N_IDE + M_U) / 4, 256, 0, stream>>>(ide, u, Ah, Bh, x2, y2, out);
  k_gemm<<<dim3(8, 32), 512, 0, stream>>>(Ah, Bh, x2, y2, partial);
  k_loss<<<256, 256, 0, stream>>>(partial, out);
}